// Round 6
// baseline (3027.252 us; speedup 1.0000x reference)
//
#include <hip/hip_runtime.h>
#include <cstdint>
#include <cstddef>

#define HH 128   // hidden
#define II 64    // input
#define OO 64    // output
#define BB 64    // batch
#define TT 2048  // time
#define NB 16    // batches per block -> 4 blocks

typedef __attribute__((ext_vector_type(8))) short short8;  // 8 bf16 (4 VGPRs)
typedef __attribute__((ext_vector_type(4))) float f32x4;   // 4 f32 acc

__device__ __forceinline__ float sigf(float x) { return 1.0f / (1.0f + __expf(-x)); }
__device__ __forceinline__ float tanh_fast(float x) {
    x = fminf(20.0f, fmaxf(-20.0f, x));
    float e = __expf(2.0f * x);
    return (e - 1.0f) / (e + 1.0f);
}
// f32 -> bf16 bits, round-to-nearest-even
__device__ __forceinline__ unsigned short f2bf(float f) {
    unsigned int u = __float_as_uint(f);
    return (unsigned short)((u + 0x7FFFu + ((u >> 16) & 1u)) >> 16);
}
__device__ __forceinline__ f32x4 mfma_bf16(short8 a, short8 b, f32x4 c) {
    return __builtin_amdgcn_mfma_f32_16x16x32_bf16(a, b, c, 0, 0, 0);
}

// A-fragment for mfma_f32_16x16x32_bf16, built from an f32 weight row.
// Lane (q = l>>4, s = l&15) holds A[row = s][k = kt*32 + q*4 + (e&3) + 16*(e>>2)].
// (k-mapping mirrors the HW-verified B layout from ds_read_b64_tr_b16: k = q*4 + j + 16r.)
__device__ __forceinline__ short8 load_afrag(const float* Wrow, int kt, int q) {
    const float* p = Wrow + kt * 32 + q * 4;
    short8 r;
#pragma unroll
    for (int j = 0; j < 4; ++j) r[j] = (short)f2bf(p[j]);
#pragma unroll
    for (int j = 0; j < 4; ++j) r[4 + j] = (short)f2bf(p[16 + j]);
    return r;
}

// Fully fused GRU + out-projection. 4 blocks x 16 batches x 8 waves.
// Wave w owns gate rows [16w, 16w+16): M-tiles w (reset), 8+w (update), 16+w (new).
// Weights are loop-invariant MFMA A-operands -> unified VGPR/AGPR file holds them
// with no per-step reload cost (MFMA reads AGPRs natively), sidestepping the
// VALU-allocator fight of R1-R5. h carry path stays f32; only matvecs see bf16.
__global__ __attribute__((amdgpu_flat_work_group_size(512, 512)))
void gru_fused_kernel(const float* __restrict__ x, const float* __restrict__ W_ih,
                      const float* __restrict__ W_hh, const float* __restrict__ b_ih,
                      const float* __restrict__ b_hh, const float* __restrict__ W_out,
                      const float* __restrict__ b_out, float* __restrict__ out) {
    // h and x_t staged as B-fragment-ordered bf16: [ktile][lane][8 elems].
    __shared__ __align__(16) unsigned short hB[2][4][64][8];  // K=128 -> 4 ktiles
    __shared__ __align__(16) unsigned short xB[2][2][64][8];  // K=64  -> 2 ktiles

    const int tid = threadIdx.x;
    const int w = tid >> 6;
    const int l = tid & 63;
    const int q = l >> 4;
    const int s = l & 15;
    const int b0 = blockIdx.x * NB;

    // ---- loop-invariant A-fragments ----
    short8 Ar[6], Az[6], Anx[2], Anh[4], Ao[4];
    {
        const int R = 16 * w + s;
        const float* rih = W_ih + (size_t)R * II;
        const float* zih = W_ih + (size_t)(HH + R) * II;
        const float* nih = W_ih + (size_t)(2 * HH + R) * II;
        const float* rhh = W_hh + (size_t)R * HH;
        const float* zhh = W_hh + (size_t)(HH + R) * HH;
        const float* nhh = W_hh + (size_t)(2 * HH + R) * HH;
#pragma unroll
        for (int kt = 0; kt < 2; ++kt) {
            Ar[kt] = load_afrag(rih, kt, q);
            Az[kt] = load_afrag(zih, kt, q);
            Anx[kt] = load_afrag(nih, kt, q);
        }
#pragma unroll
        for (int kt = 0; kt < 4; ++kt) {
            Ar[2 + kt] = load_afrag(rhh, kt, q);
            Az[2 + kt] = load_afrag(zhh, kt, q);
            Anh[kt] = load_afrag(nhh, kt, q);
        }
        if (w < 4) {
            const float* orow = W_out + (size_t)R * HH;
#pragma unroll
            for (int kt = 0; kt < 4; ++kt) Ao[kt] = load_afrag(orow, kt, q);
        }
    }

    // Per-lane biases: C/D row = 16w + q*4 + j (m89-verified layout).
    float br[4], bz[4], bnx[4], bnh[4], bo[4];
#pragma unroll
    for (int j = 0; j < 4; ++j) {
        const int R = 16 * w + q * 4 + j;
        br[j] = b_ih[R] + b_hh[R];
        bz[j] = b_ih[HH + R] + b_hh[HH + R];
        bnx[j] = b_ih[2 * HH + R];
        bnh[j] = b_hh[2 * HH + R];
        bo[j] = (w < 4) ? b_out[R] : 0.0f;
    }

    // h_{-1} = 0
    if (tid < 256) ((uint4*)&hB[0][0][0][0])[tid] = make_uint4(0, 0, 0, 0);

    // ---- x staging (threads 256..511): 2-step-deep prefetch ----
    const int st = tid - 256;
    const float* xsrc = nullptr;
    int xkt = 0, xlt = 0, xro = 0;
    float4 pcur = make_float4(0, 0, 0, 0), pnext = make_float4(0, 0, 0, 0);
    if (tid >= 256) {
        const int bb = st >> 4;            // local batch 0..15
        const int i0 = (st & 15) * 4;      // k-offset 0..60
        xsrc = x + ((size_t)(b0 + bb) * TT) * II + i0;
        xkt = (st >> 3) & 1;               // i0>>5
        xlt = (st & 3) * 16 + bb;          // target lane = ((i0>>2)&3)*16 + col
        xro = ((st >> 2) & 1) * 4;         // elem offset: (i0>>4 & 1)*4
        float4 p0 = *(const float4*)(xsrc);                 // x_0
        unsigned int u0 = f2bf(p0.x) | ((unsigned int)f2bf(p0.y) << 16);
        unsigned int u1 = f2bf(p0.z) | ((unsigned int)f2bf(p0.w) << 16);
        *(uint2*)&xB[0][xkt][xlt][xro] = make_uint2(u0, u1);
        pcur = *(const float4*)(xsrc + (size_t)1 * II);     // x_1
        pnext = *(const float4*)(xsrc + (size_t)2 * II);    // x_2
    }
    __syncthreads();

    float hprev[4] = {0.f, 0.f, 0.f, 0.f};
    const f32x4 z4 = {0.f, 0.f, 0.f, 0.f};
    float* outp = out + ((size_t)(b0 + s) * TT) * OO + 16 * w + q * 4;

    for (int t = 0; t < TT; ++t) {
        const int cur = t & 1, nxt = cur ^ 1;

        const short8 hb0 = *(const short8*)&hB[cur][0][l][0];
        const short8 hb1 = *(const short8*)&hB[cur][1][l][0];
        const short8 hb2 = *(const short8*)&hB[cur][2][l][0];
        const short8 hb3 = *(const short8*)&hB[cur][3][l][0];
        const short8 xb0 = *(const short8*)&xB[cur][0][l][0];
        const short8 xb1 = *(const short8*)&xB[cur][1][l][0];

        f32x4 Cr = z4, Cz = z4, Cnx = z4, Cnh = z4;
        Cr = mfma_bf16(Ar[0], xb0, Cr);
        Cr = mfma_bf16(Ar[1], xb1, Cr);
        Cz = mfma_bf16(Az[0], xb0, Cz);
        Cz = mfma_bf16(Az[1], xb1, Cz);
        Cnx = mfma_bf16(Anx[0], xb0, Cnx);
        Cnx = mfma_bf16(Anx[1], xb1, Cnx);
        Cr = mfma_bf16(Ar[2], hb0, Cr);
        Cr = mfma_bf16(Ar[3], hb1, Cr);
        Cr = mfma_bf16(Ar[4], hb2, Cr);
        Cr = mfma_bf16(Ar[5], hb3, Cr);
        Cz = mfma_bf16(Az[2], hb0, Cz);
        Cz = mfma_bf16(Az[3], hb1, Cz);
        Cz = mfma_bf16(Az[4], hb2, Cz);
        Cz = mfma_bf16(Az[5], hb3, Cz);
        Cnh = mfma_bf16(Anh[0], hb0, Cnh);
        Cnh = mfma_bf16(Anh[1], hb1, Cnh);
        Cnh = mfma_bf16(Anh[2], hb2, Cnh);
        Cnh = mfma_bf16(Anh[3], hb3, Cnh);

        // fused out-projection for step t-1 (h_{t-1} frags already loaded)
        if (w < 4 && t > 0) {
            f32x4 Co = z4;
            Co = mfma_bf16(Ao[0], hb0, Co);
            Co = mfma_bf16(Ao[1], hb1, Co);
            Co = mfma_bf16(Ao[2], hb2, Co);
            Co = mfma_bf16(Ao[3], hb3, Co);
            float4 ov = make_float4(Co[0] + bo[0], Co[1] + bo[1],
                                    Co[2] + bo[2], Co[3] + bo[3]);
            *(float4*)(outp + (size_t)(t - 1) * OO) = ov;
        }

        // gates; f32 carry path for h
        unsigned short hb16[4];
#pragma unroll
        for (int j = 0; j < 4; ++j) {
            const float r = sigf(Cr[j] + br[j]);
            const float zz = sigf(Cz[j] + bz[j]);
            const float n = tanh_fast(Cnx[j] + bnx[j] + r * (Cnh[j] + bnh[j]));
            const float h = (1.0f - zz) * n + zz * hprev[j];
            hprev[j] = h;
            hb16[j] = f2bf(h);
        }
        // write h_t into next B-frag buffer: rows 16w+q*4+j land at THIS lane's
        // slot: ktile w>>1, elem base (w&1)*4 (derived from verified layouts).
        {
            unsigned int u0 = hb16[0] | ((unsigned int)hb16[1] << 16);
            unsigned int u1 = hb16[2] | ((unsigned int)hb16[3] << 16);
            *(uint2*)&hB[nxt][w >> 1][l][(w & 1) * 4] = make_uint2(u0, u1);
        }
        // stage x_{t+1} frags; issue load for x_{t+3}
        if (tid >= 256) {
            unsigned int u0 = f2bf(pcur.x) | ((unsigned int)f2bf(pcur.y) << 16);
            unsigned int u1 = f2bf(pcur.z) | ((unsigned int)f2bf(pcur.w) << 16);
            *(uint2*)&xB[nxt][xkt][xlt][xro] = make_uint2(u0, u1);
            pcur = pnext;
            const int tl = (t + 3 < TT) ? (t + 3) : (TT - 1);
            pnext = *(const float4*)(xsrc + (size_t)tl * II);
        }
        __syncthreads();
    }

    // epilogue: out for t = TT-1 (h_{TT-1} is in hB[TT & 1] = hB[0])
    if (w < 4) {
        const short8 hb0 = *(const short8*)&hB[0][0][l][0];
        const short8 hb1 = *(const short8*)&hB[0][1][l][0];
        const short8 hb2 = *(const short8*)&hB[0][2][l][0];
        const short8 hb3 = *(const short8*)&hB[0][3][l][0];
        f32x4 Co = z4;
        Co = mfma_bf16(Ao[0], hb0, Co);
        Co = mfma_bf16(Ao[1], hb1, Co);
        Co = mfma_bf16(Ao[2], hb2, Co);
        Co = mfma_bf16(Ao[3], hb3, Co);
        float4 ov = make_float4(Co[0] + bo[0], Co[1] + bo[1],
                                Co[2] + bo[2], Co[3] + bo[3]);
        *(float4*)(outp + (size_t)(TT - 1) * OO) = ov;
    }
}

extern "C" void kernel_launch(void* const* d_in, const int* in_sizes, int n_in,
                              void* d_out, int out_size, void* d_ws, size_t ws_size,
                              hipStream_t stream) {
    const float* x     = (const float*)d_in[0];
    const float* W_ih  = (const float*)d_in[1];
    const float* W_hh  = (const float*)d_in[2];
    const float* b_ih  = (const float*)d_in[3];
    const float* b_hh  = (const float*)d_in[4];
    const float* W_out = (const float*)d_in[5];
    const float* b_out = (const float*)d_in[6];
    float* out = (float*)d_out;
    (void)d_ws; (void)ws_size;

    gru_fused_kernel<<<BB / NB, 512, 0, stream>>>(
        x, W_ih, W_hh, b_ih, b_hh, W_out, b_out, out);
}

// Round 7
// 1595.818 us; speedup vs baseline: 1.8970x; 1.8970x over previous
//
#include <hip/hip_runtime.h>
#include <cstdint>
#include <cstddef>

#define HH 128   // hidden
#define II 64    // input
#define OO 64    // output
#define G3 384   // 3*H
#define BB 64    // batch
#define TT 2048  // time
#define NB 16    // batches per scan block -> 4 blocks
#define QR 96    // G3/4 "quad rows" in the gx workspace layout

typedef __attribute__((ext_vector_type(8))) short short8;  // 8 bf16
typedef __attribute__((ext_vector_type(4))) float f32x4;   // 4 f32

__device__ __forceinline__ float sigf(float x) {
    // 1/(1+2^(-x*log2e)) via raw v_exp + v_rcp (no Newton refinement)
    float e = __builtin_amdgcn_exp2f(-1.442695041f * x);
    return __builtin_amdgcn_rcpf(1.0f + e);
}
__device__ __forceinline__ float tanh_fast(float x) {
    x = fminf(10.0f, fmaxf(-10.0f, x));
    float e = __builtin_amdgcn_exp2f(2.885390082f * x);  // exp(2x)
    return (e - 1.0f) * __builtin_amdgcn_rcpf(e + 1.0f);
}
// f32 -> bf16 bits, round-to-nearest-even
__device__ __forceinline__ unsigned short f2bf(float f) {
    unsigned int u = __float_as_uint(f);
    return (unsigned short)((u + 0x7FFFu + ((u >> 16) & 1u)) >> 16);
}
__device__ __forceinline__ f32x4 mfma_bf16(short8 a, short8 b, f32x4 c) {
    return __builtin_amdgcn_mfma_f32_16x16x32_bf16(a, b, c, 0, 0, 0);
}
__device__ __forceinline__ float dot4(float4 a, float4 b) {
    return a.x * b.x + a.y * b.y + a.z * b.z + a.w * b.w;
}

// A-fragment for mfma_f32_16x16x32_bf16 from an f32 weight row.
// Lane (q=l>>4, s=l&15) holds A[row=s][k = kt*32 + q*4 + (e&3) + 16*(e>>2)].
__device__ __forceinline__ short8 load_afrag(const float* Wrow, int kt, int q) {
    const float* p = Wrow + kt * 32 + q * 4;
    short8 r;
#pragma unroll
    for (int j = 0; j < 4; ++j) r[j] = (short)f2bf(p[j]);
#pragma unroll
    for (int j = 0; j < 4; ++j) r[4 + j] = (short)f2bf(p[16 + j]);
    return r;
}

// ------- gx = x @ W_ih^T + b_ih, stored lane-matched for the scan --------
// gxws[blk][t][qr][s][j] f32 : blk = b>>4, s = b&15, qr = R>>2, j = R&3.
// Scan lane (w,q,s) then reads its 4 gate-row inits as ONE float4 at
// qr = {4w+q, 32+4w+q, 64+4w+q}.
__global__ __launch_bounds__(768) void gru_gx_kernel(
        const float* __restrict__ x, const float* __restrict__ W_ih,
        const float* __restrict__ b_ih, float* __restrict__ gxws) {
    __shared__ __align__(16) float sx[32][II];
    const int tid = threadIdx.x;
    const int g = tid >> 1;      // gate row 0..383
    const int kh = tid & 1;      // k half
    const int row0 = blockIdx.x * 32;           // row = b*TT + t
    const int b = row0 >> 11;                   // row0 / TT
    const int t0 = row0 & (TT - 1);
    const size_t base = ((size_t)(b >> 4) * TT) * (QR * 64)
                      + (size_t)(g >> 2) * 64 + (size_t)(b & 15) * 4 + (g & 3);

    float4 w4[8];
    {
        const float4* Wp = (const float4*)(W_ih + (size_t)g * II + kh * 32);
#pragma unroll
        for (int i = 0; i < 8; ++i) w4[i] = Wp[i];
    }
    const float bias = b_ih[g];

    for (int i = tid; i < 32 * II; i += 768)
        ((float*)sx)[i] = x[(size_t)row0 * II + i];
    __syncthreads();

#pragma unroll 4
    for (int r = 0; r < 32; ++r) {
        const float4* sx4 = (const float4*)sx[r] + kh * 8;
        float acc = 0.0f;
#pragma unroll
        for (int i = 0; i < 8; ++i) acc += dot4(w4[i], sx4[i]);
        acc += __shfl_xor(acc, 1);
        if (kh == 0)
            gxws[base + (size_t)(t0 + r) * (QR * 64)] = acc + bias;
    }
}

// ------- fused scan + out-projection: 4 blocks x 16 batches x 8 waves ----
// Wave w owns h rows [16w,16w+16) (gate M-tiles for r/z/n). Weights are
// loop-invariant MFMA A-operands (unified VGPR/AGPR file -> no per-step
// reload). h carry path f32; matvecs bf16. One barrier per step. gx for
// step t+1 prefetched at the TOP of step t so the pre-barrier vmcnt drain
// costs nothing (R6 issued it right before the barrier).
__global__ __attribute__((amdgpu_flat_work_group_size(512, 512)))
void gru_scan_kernel(const float* __restrict__ gxws,
                     const float* __restrict__ W_hh, const float* __restrict__ b_hh,
                     const float* __restrict__ W_out, const float* __restrict__ b_out,
                     float* __restrict__ out) {
    __shared__ __align__(16) unsigned short hB[2][4][64][8];

    const int tid = threadIdx.x;
    const int w = tid >> 6;
    const int l = tid & 63;
    const int q = l >> 4;
    const int s = l & 15;
    const int blk = blockIdx.x;

    // loop-invariant A-fragments (R6-verified mapping)
    short8 Ar[4], Az[4], An[4], Ao[4];
    {
        const int R = 16 * w + s;
        const float* rhh = W_hh + (size_t)R * HH;
        const float* zhh = W_hh + (size_t)(HH + R) * HH;
        const float* nhh = W_hh + (size_t)(2 * HH + R) * HH;
#pragma unroll
        for (int kt = 0; kt < 4; ++kt) {
            Ar[kt] = load_afrag(rhh, kt, q);
            Az[kt] = load_afrag(zhh, kt, q);
            An[kt] = load_afrag(nhh, kt, q);
        }
        if (w < 4) {
            const float* orow = W_out + (size_t)R * HH;
#pragma unroll
            for (int kt = 0; kt < 4; ++kt) Ao[kt] = load_afrag(orow, kt, q);
        }
    }

    // per-lane biases: C/D row = 16w + q*4 + j
    float bhr[4], bhz[4], bhn[4], bo[4];
#pragma unroll
    for (int j = 0; j < 4; ++j) {
        const int R = 16 * w + q * 4 + j;
        bhr[j] = b_hh[R];
        bhz[j] = b_hh[HH + R];
        bhn[j] = b_hh[2 * HH + R];
        bo[j] = (w < 4) ? b_out[R] : 0.0f;
    }

    if (tid < 256) ((uint4*)&hB[0][0][0][0])[tid] = make_uint4(0, 0, 0, 0);

    // gx pointers: qr = 4w+q (+0 / +32 / +64 for r/z/n), col s
    const float* gbase = gxws + (size_t)blk * TT * (QR * 64)
                       + (size_t)(4 * w + q) * 64 + (size_t)s * 4;
    f32x4 gr = *(const f32x4*)(gbase);
    f32x4 gz = *(const f32x4*)(gbase + 32 * 64);
    f32x4 gn = *(const f32x4*)(gbase + 64 * 64);
    __syncthreads();

    float hprev[4] = {0.f, 0.f, 0.f, 0.f};
    const f32x4 z4 = {0.f, 0.f, 0.f, 0.f};
    float* outp = out + ((size_t)(blk * NB + s) * TT) * OO + 16 * w + q * 4;

    for (int t = 0; t < TT; ++t) {
        const int cur = t & 1, nxt = cur ^ 1;

        // prefetch gx for t+1 FIRST (hides under MFMA+gates)
        const float* gq = gbase + (size_t)((t + 1 < TT) ? t + 1 : t) * (QR * 64);
        const f32x4 pr = *(const f32x4*)(gq);
        const f32x4 pz = *(const f32x4*)(gq + 32 * 64);
        const f32x4 pn = *(const f32x4*)(gq + 64 * 64);

        const short8 hb0 = *(const short8*)&hB[cur][0][l][0];
        const short8 hb1 = *(const short8*)&hB[cur][1][l][0];
        const short8 hb2 = *(const short8*)&hB[cur][2][l][0];
        const short8 hb3 = *(const short8*)&hB[cur][3][l][0];

        f32x4 Cr = gr, Cz = gz, Cn = z4;
        Cr = mfma_bf16(Ar[0], hb0, Cr);
        Cr = mfma_bf16(Ar[1], hb1, Cr);
        Cr = mfma_bf16(Ar[2], hb2, Cr);
        Cr = mfma_bf16(Ar[3], hb3, Cr);
        Cz = mfma_bf16(Az[0], hb0, Cz);
        Cz = mfma_bf16(Az[1], hb1, Cz);
        Cz = mfma_bf16(Az[2], hb2, Cz);
        Cz = mfma_bf16(Az[3], hb3, Cz);
        Cn = mfma_bf16(An[0], hb0, Cn);
        Cn = mfma_bf16(An[1], hb1, Cn);
        Cn = mfma_bf16(An[2], hb2, Cn);
        Cn = mfma_bf16(An[3], hb3, Cn);

        // fused out-projection for step t-1 (h_{t-1} frags already loaded)
        if (w < 4 && t > 0) {
            f32x4 Co = z4;
            Co = mfma_bf16(Ao[0], hb0, Co);
            Co = mfma_bf16(Ao[1], hb1, Co);
            Co = mfma_bf16(Ao[2], hb2, Co);
            Co = mfma_bf16(Ao[3], hb3, Co);
            *(float4*)(outp + (size_t)(t - 1) * OO) =
                make_float4(Co[0] + bo[0], Co[1] + bo[1],
                            Co[2] + bo[2], Co[3] + bo[3]);
        }

        // gates; f32 carry path
        unsigned short hb16[4];
#pragma unroll
        for (int j = 0; j < 4; ++j) {
            const float r = sigf(Cr[j] + bhr[j]);
            const float zz = sigf(Cz[j] + bhz[j]);
            const float n = tanh_fast(gn[j] + r * (Cn[j] + bhn[j]));
            const float h = (1.0f - zz) * n + zz * hprev[j];
            hprev[j] = h;
            hb16[j] = f2bf(h);
        }
        {
            unsigned int u0 = hb16[0] | ((unsigned int)hb16[1] << 16);
            unsigned int u1 = hb16[2] | ((unsigned int)hb16[3] << 16);
            *(uint2*)&hB[nxt][w >> 1][l][(w & 1) * 4] = make_uint2(u0, u1);
        }
        gr = pr; gz = pz; gn = pn;
        __syncthreads();
    }

    // epilogue: out for t = TT-1 (h_{TT-1} lives in hB[0])
    if (w < 4) {
        const short8 hb0 = *(const short8*)&hB[0][0][l][0];
        const short8 hb1 = *(const short8*)&hB[0][1][l][0];
        const short8 hb2 = *(const short8*)&hB[0][2][l][0];
        const short8 hb3 = *(const short8*)&hB[0][3][l][0];
        f32x4 Co = z4;
        Co = mfma_bf16(Ao[0], hb0, Co);
        Co = mfma_bf16(Ao[1], hb1, Co);
        Co = mfma_bf16(Ao[2], hb2, Co);
        Co = mfma_bf16(Ao[3], hb3, Co);
        *(float4*)(outp + (size_t)(TT - 1) * OO) =
            make_float4(Co[0] + bo[0], Co[1] + bo[1],
                        Co[2] + bo[2], Co[3] + bo[3]);
    }
}

extern "C" void kernel_launch(void* const* d_in, const int* in_sizes, int n_in,
                              void* d_out, int out_size, void* d_ws, size_t ws_size,
                              hipStream_t stream) {
    const float* x     = (const float*)d_in[0];
    const float* W_ih  = (const float*)d_in[1];
    const float* W_hh  = (const float*)d_in[2];
    const float* b_ih  = (const float*)d_in[3];
    const float* b_hh  = (const float*)d_in[4];
    const float* W_out = (const float*)d_in[5];
    const float* b_out = (const float*)d_in[6];
    float* out = (float*)d_out;

    // ws >= 268MB established (tier-A path ran in R1-R5); gx needs 201MB.
    float* gxws = (float*)d_ws;

    gru_gx_kernel<<<(BB * TT) / 32, 768, 0, stream>>>(x, W_ih, b_ih, gxws);
    gru_scan_kernel<<<BB / NB, 512, 0, stream>>>(
        gxws, W_hh, b_hh, W_out, b_out, out);
}

// Round 8
// 1377.178 us; speedup vs baseline: 2.1982x; 1.1588x over previous
//
#include <hip/hip_runtime.h>
#include <cstdint>
#include <cstddef>

#define HH 128   // hidden
#define II 64    // input
#define OO 64    // output
#define G3 384   // 3*H
#define BB 64    // batch
#define TT 2048  // time
#define NB 16    // batches per scan block -> 4 blocks
#define GXSTEP 6144  // floats per (blk, t) slab: 32 qr * 16 s * 3 gates * 4

typedef __attribute__((ext_vector_type(8))) short short8;  // 8 bf16
typedef __attribute__((ext_vector_type(4))) float f32x4;   // 4 f32

// inf-safe sigmoid / tanh on exp2+rcp (trans pipe), no clamps needed:
// x->-inf: exp2(+big)=inf -> rcp(inf)=0 ; x->+inf: exp2(-big)=0 -> rcp(1)=1.
__device__ __forceinline__ float sigf(float x) {
    float e = __builtin_amdgcn_exp2f(-1.442695041f * x);
    return __builtin_amdgcn_rcpf(1.0f + e);
}
__device__ __forceinline__ float tanh_fast(float x) {
    // 2*sigmoid(2x) - 1
    float e = __builtin_amdgcn_exp2f(-2.885390082f * x);
    return fmaf(2.0f, __builtin_amdgcn_rcpf(1.0f + e), -1.0f);
}
// f32 -> bf16 bits, RNE (for weight fragments; one-time cost)
__device__ __forceinline__ unsigned short f2bf(float f) {
    unsigned int u = __float_as_uint(f);
    return (unsigned short)((u + 0x7FFFu + ((u >> 16) & 1u)) >> 16);
}
// packed f32x2 -> bf16x2 in one VALU op (T12 primitive)
__device__ __forceinline__ unsigned int cvt_pk_bf16(float lo, float hi) {
    unsigned int r;
    asm("v_cvt_pk_bf16_f32 %0, %1, %2" : "=v"(r) : "v"(lo), "v"(hi));
    return r;
}
__device__ __forceinline__ f32x4 mfma_bf16(short8 a, short8 b, f32x4 c) {
    return __builtin_amdgcn_mfma_f32_16x16x32_bf16(a, b, c, 0, 0, 0);
}
__device__ __forceinline__ float dot4(float4 a, float4 b) {
    return a.x * b.x + a.y * b.y + a.z * b.z + a.w * b.w;
}

// A-fragment for mfma_f32_16x16x32_bf16 from an f32 weight row.
// Lane (q=l>>4, s=l&15) holds A[row=s][k = kt*32 + q*4 + (e&3) + 16*(e>>2)].
__device__ __forceinline__ short8 load_afrag(const float* Wrow, int kt, int q) {
    const float* p = Wrow + kt * 32 + q * 4;
    short8 r;
#pragma unroll
    for (int j = 0; j < 4; ++j) r[j] = (short)f2bf(p[j]);
#pragma unroll
    for (int j = 0; j < 4; ++j) r[4 + j] = (short)f2bf(p[16 + j]);
    return r;
}

// ------- gx = x @ W_ih^T + b_ih (+ b_hh for r,z gates), lane-matched ------
// Layout: gxws[blk][t][qr][s][gate][4] f32, qr = R>>2 (R = row within gate),
// s = batch&15, j = R&3. Scan lane (w,q,s) reads its r/z/n float4s from ONE
// base at byte offsets 0/16/32.
__global__ __launch_bounds__(768) void gru_gx_kernel(
        const float* __restrict__ x, const float* __restrict__ W_ih,
        const float* __restrict__ b_ih, const float* __restrict__ b_hh,
        float* __restrict__ gxws) {
    __shared__ __align__(16) float sx[32][II];
    const int tid = threadIdx.x;
    const int g = tid >> 1;      // gate row 0..383
    const int kh = tid & 1;      // k half
    const int row0 = blockIdx.x * 32;           // row = b*TT + t
    const int b = row0 >> 11;                   // row0 / TT
    const int t0 = row0 & (TT - 1);
    const int gate = g >> 7;                    // 0=r 1=z 2=n
    const int R = g & 127;
    const size_t base = ((size_t)(b >> 4) * TT) * GXSTEP
                      + ((size_t)(R >> 2) * 16 + (b & 15)) * 12
                      + (size_t)gate * 4 + (R & 3);

    float4 w4[8];
    {
        const float4* Wp = (const float4*)(W_ih + (size_t)g * II + kh * 32);
#pragma unroll
        for (int i = 0; i < 8; ++i) w4[i] = Wp[i];
    }
    // fold b_hh into r,z gate inits (their MFMA-side bias); n keeps b_hh apart
    const float bias = b_ih[g] + ((gate < 2) ? b_hh[g] : 0.0f);

    for (int i = tid; i < 32 * II; i += 768)
        ((float*)sx)[i] = x[(size_t)row0 * II + i];
    __syncthreads();

#pragma unroll 4
    for (int r = 0; r < 32; ++r) {
        const float4* sx4 = (const float4*)sx[r] + kh * 8;
        float acc = 0.0f;
#pragma unroll
        for (int i = 0; i < 8; ++i) acc += dot4(w4[i], sx4[i]);
        acc += __shfl_xor(acc, 1);
        if (kh == 0)
            gxws[base + (size_t)(t0 + r) * GXSTEP] = acc + bias;
    }
}

// ------- fused scan + out-projection: 4 blocks x 16 batches x 8 waves ----
// Weights live as loop-invariant MFMA A-fragments (unified VGPR/AGPR file).
// KEY R8 change: raw s_barrier with lgkmcnt(0) ONLY (no vmcnt drain), so the
// 2-step-deep gx prefetch stays in flight across barriers; __syncthreads()'s
// compiler-emitted vmcnt(0) was serializing HBM latency into every step.
__global__ __attribute__((amdgpu_flat_work_group_size(512, 512)))
void gru_scan_kernel(const float* __restrict__ gxws,
                     const float* __restrict__ W_hh, const float* __restrict__ b_hh,
                     const float* __restrict__ W_out, const float* __restrict__ b_out,
                     float* __restrict__ out) {
    __shared__ __align__(16) unsigned short hB[2][4][64][8];

    const int tid = threadIdx.x;
    const int w = tid >> 6;
    const int l = tid & 63;
    const int q = l >> 4;
    const int s = l & 15;
    const int blk = blockIdx.x;

    // loop-invariant A-fragments (R6/R7-verified mapping)
    short8 Ar[4], Az[4], An[4], Ao[4];
    {
        const int R = 16 * w + s;
        const float* rhh = W_hh + (size_t)R * HH;
        const float* zhh = W_hh + (size_t)(HH + R) * HH;
        const float* nhh = W_hh + (size_t)(2 * HH + R) * HH;
#pragma unroll
        for (int kt = 0; kt < 4; ++kt) {
            Ar[kt] = load_afrag(rhh, kt, q);
            Az[kt] = load_afrag(zhh, kt, q);
            An[kt] = load_afrag(nhh, kt, q);
        }
        if (w < 4) {
            const float* orow = W_out + (size_t)R * HH;
#pragma unroll
            for (int kt = 0; kt < 4; ++kt) Ao[kt] = load_afrag(orow, kt, q);
        }
    }

    // per-lane n-gate bias (C/D row = 16w + q*4 + j) as Cn accumulator init,
    // and out-proj bias
    f32x4 bhn_v;
    float bo[4];
#pragma unroll
    for (int j = 0; j < 4; ++j) {
        const int R = 16 * w + q * 4 + j;
        bhn_v[j] = b_hh[2 * HH + R];
        bo[j] = (w < 4) ? b_out[R] : 0.0f;
    }

    if (tid < 256) ((uint4*)&hB[0][0][0][0])[tid] = make_uint4(0, 0, 0, 0);

    // gx base for this lane; r/z/n at byte offsets 0/16/32
    const float* gbase = gxws + (size_t)blk * TT * GXSTEP
                       + ((size_t)(4 * w + q) * 16 + s) * 12;
    f32x4 g0r = *(const f32x4*)(gbase);
    f32x4 g0z = *(const f32x4*)(gbase + 4);
    f32x4 g0n = *(const f32x4*)(gbase + 8);
    f32x4 g1r = *(const f32x4*)(gbase + GXSTEP);
    f32x4 g1z = *(const f32x4*)(gbase + GXSTEP + 4);
    f32x4 g1n = *(const f32x4*)(gbase + GXSTEP + 8);
    const float* gpre = gbase + 2 * GXSTEP;  // overruns by <=2 slabs at the
                                             // tail: reads stable ws garbage,
                                             // never used in arithmetic
    __syncthreads();

    float hprev[4] = {0.f, 0.f, 0.f, 0.f};
    const f32x4 z4 = {0.f, 0.f, 0.f, 0.f};
    float* outp = out + ((size_t)(blk * NB + s) * TT) * OO + 16 * w + q * 4;

    // One sub-step. CUR is a literal (0/1) -> all LDS indices static.
    // GR/GZ are reloaded mid-step (dead after C-init), GN after the gates:
    // the new values' first use is the NEXT same-parity sub-step -> ~1.5
    // steps of slack for the global load, no register copies.
#define SUBSTEP(CUR, GR, GZ, GN, DO_OUT, T)                                   \
    {                                                                         \
        const short8 hb0 = *(const short8*)&hB[CUR][0][l][0];                 \
        const short8 hb1 = *(const short8*)&hB[CUR][1][l][0];                 \
        const short8 hb2 = *(const short8*)&hB[CUR][2][l][0];                 \
        const short8 hb3 = *(const short8*)&hB[CUR][3][l][0];                 \
        f32x4 Cr = GR, Cz = GZ, Cn = bhn_v;                                   \
        GR = *(const f32x4*)(gpre);                                           \
        GZ = *(const f32x4*)(gpre + 4);                                       \
        Cr = mfma_bf16(Ar[0], hb0, Cr);                                       \
        Cr = mfma_bf16(Ar[1], hb1, Cr);                                       \
        Cr = mfma_bf16(Ar[2], hb2, Cr);                                       \
        Cr = mfma_bf16(Ar[3], hb3, Cr);                                       \
        Cz = mfma_bf16(Az[0], hb0, Cz);                                       \
        Cz = mfma_bf16(Az[1], hb1, Cz);                                       \
        Cz = mfma_bf16(Az[2], hb2, Cz);                                       \
        Cz = mfma_bf16(Az[3], hb3, Cz);                                       \
        Cn = mfma_bf16(An[0], hb0, Cn);                                       \
        Cn = mfma_bf16(An[1], hb1, Cn);                                       \
        Cn = mfma_bf16(An[2], hb2, Cn);                                       \
        Cn = mfma_bf16(An[3], hb3, Cn);                                       \
        if ((DO_OUT) && w < 4) {                                              \
            f32x4 Co = z4;                                                    \
            Co = mfma_bf16(Ao[0], hb0, Co);                                   \
            Co = mfma_bf16(Ao[1], hb1, Co);                                   \
            Co = mfma_bf16(Ao[2], hb2, Co);                                   \
            Co = mfma_bf16(Ao[3], hb3, Co);                                   \
            *(float4*)(outp + (size_t)((T) - 1) * OO) =                       \
                make_float4(Co[0] + bo[0], Co[1] + bo[1],                     \
                            Co[2] + bo[2], Co[3] + bo[3]);                    \
        }                                                                     \
        float hnew[4];                                                        \
        _Pragma("unroll")                                                     \
        for (int j = 0; j < 4; ++j) {                                         \
            const float r = sigf(Cr[j]);                                      \
            const float zz = sigf(Cz[j]);                                     \
            const float n = tanh_fast(fmaf(r, Cn[j], GN[j]));                 \
            hnew[j] = fmaf(zz, hprev[j] - n, n);                              \
            hprev[j] = hnew[j];                                               \
        }                                                                     \
        GN = *(const f32x4*)(gpre + 8);                                       \
        gpre += GXSTEP;                                                       \
        {                                                                     \
            unsigned int u0 = cvt_pk_bf16(hnew[0], hnew[1]);                  \
            unsigned int u1 = cvt_pk_bf16(hnew[2], hnew[3]);                  \
            *(uint2*)&hB[CUR ^ 1][w >> 1][l][(w & 1) * 4] = make_uint2(u0, u1);\
        }                                                                     \
        asm volatile("s_waitcnt lgkmcnt(0)" ::: "memory");                    \
        __builtin_amdgcn_s_barrier();                                         \
        asm volatile("" ::: "memory");                                        \
    }

    SUBSTEP(0, g0r, g0z, g0n, false, 0);  // t = 0 (no out yet)
    SUBSTEP(1, g1r, g1z, g1n, true, 1);   // t = 1
    for (int t = 2; t < TT; t += 2) {
        SUBSTEP(0, g0r, g0z, g0n, true, t);
        SUBSTEP(1, g1r, g1z, g1n, true, t + 1);
    }
#undef SUBSTEP

    // epilogue: out for t = TT-1 (h_{TT-1} lives in hB[0])
    if (w < 4) {
        const short8 hb0 = *(const short8*)&hB[0][0][l][0];
        const short8 hb1 = *(const short8*)&hB[0][1][l][0];
        const short8 hb2 = *(const short8*)&hB[0][2][l][0];
        const short8 hb3 = *(const short8*)&hB[0][3][l][0];
        f32x4 Co = z4;
        Co = mfma_bf16(Ao[0], hb0, Co);
        Co = mfma_bf16(Ao[1], hb1, Co);
        Co = mfma_bf16(Ao[2], hb2, Co);
        Co = mfma_bf16(Ao[3], hb3, Co);
        *(float4*)(outp + (size_t)(TT - 1) * OO) =
            make_float4(Co[0] + bo[0], Co[1] + bo[1],
                        Co[2] + bo[2], Co[3] + bo[3]);
    }
}

extern "C" void kernel_launch(void* const* d_in, const int* in_sizes, int n_in,
                              void* d_out, int out_size, void* d_ws, size_t ws_size,
                              hipStream_t stream) {
    const float* x     = (const float*)d_in[0];
    const float* W_ih  = (const float*)d_in[1];
    const float* W_hh  = (const float*)d_in[2];
    const float* b_ih  = (const float*)d_in[3];
    const float* b_hh  = (const float*)d_in[4];
    const float* W_out = (const float*)d_in[5];
    const float* b_out = (const float*)d_in[6];
    float* out = (float*)d_out;

    float* gxws = (float*)d_ws;  // 201 MB + 48 KB overrun; ws >= 268 MB (R1-R5)

    gru_gx_kernel<<<(BB * TT) / 32, 768, 0, stream>>>(x, W_ih, b_ih, b_hh, gxws);
    gru_scan_kernel<<<BB / NB, 512, 0, stream>>>(
        gxws, W_hh, b_hh, W_out, b_out, out);
}